// Round 13
// baseline (289.537 us; speedup 1.0000x reference)
//
#include <hip/hip_runtime.h>

typedef unsigned short u16;
typedef unsigned int u32;
typedef __attribute__((ext_vector_type(8))) __bf16 bf16x8;
typedef __attribute__((ext_vector_type(8))) u16 u16x8;
typedef __attribute__((ext_vector_type(4))) float f32x4;
typedef __attribute__((ext_vector_type(2))) u32 u32x2;

#define SEQ 4096
#define HID 1152
#define NHEAD 16
#define HDIM 72
#define FF 4304
#define FFP 4352
#define H3 3456
#define H3P 3584  // QKV logical N padded to 14*256 (pad cols alias Wo rows; stores guarded)

__device__ __forceinline__ u16 f2bf(float f) {
  u32 u = __builtin_bit_cast(u32, f);
  u32 r = u + 0x7fffu + ((u >> 16) & 1u);
  return (u16)(r >> 16);
}
__device__ __forceinline__ float bf2f(u16 h) {
  return __builtin_bit_cast(float, (u32)h << 16);
}
__device__ __forceinline__ float bflo(u32 u) { return __builtin_bit_cast(float, u << 16); }
__device__ __forceinline__ float bfhi(u32 u) { return __builtin_bit_cast(float, u & 0xffff0000u); }

typedef const __attribute__((address_space(1))) void* gas_t;
typedef __attribute__((address_space(3))) void* las_t;
__device__ __forceinline__ void load_lds16(const void* g, void* l) {
  __builtin_amdgcn_global_load_lds((gas_t)(unsigned long long)g,
                                   (las_t)(u32)(unsigned long long)l, 16, 0, 0);
}

__device__ __forceinline__ float gelu_fast(float x) {
  float z = 0.7978845608f * (x + 0.044715f * x * x * x);
  return x / (1.f + __expf(-2.f * z));
}

// ---------------- weight converts ----------------
__global__ __launch_bounds__(256) void cvt4x4_k(const float* __restrict__ a,
                                                const float* __restrict__ b,
                                                const float* __restrict__ c,
                                                const float* __restrict__ d,
                                                u16* __restrict__ out, int n4) {
  int i = blockIdx.x * 256 + threadIdx.x;
  if (i >= n4) return;
  const float* in = (blockIdx.y == 0) ? a : (blockIdx.y == 1) ? b : (blockIdx.y == 2) ? c : d;
  f32x4 f = ((const f32x4*)in)[i];
  u32x2 o;
  o[0] = (u32)f2bf(f[0]) | ((u32)f2bf(f[1]) << 16);
  o[1] = (u32)f2bf(f[2]) | ((u32)f2bf(f[3]) << 16);
  ((u32x2*)(out + (size_t)blockIdx.y * n4 * 4))[i] = o;
}

__global__ __launch_bounds__(256) void cvt4_pad_k(const float* __restrict__ in,
                                                  u16* __restrict__ out,
                                                  int rows, int sc, int dc) {
  int i = blockIdx.x * 256 + threadIdx.x;
  long long n4 = (long long)rows * dc / 4;
  if (i >= n4) return;
  long long idx = (long long)i * 4;
  int r = (int)(idx / dc);
  int c = (int)(idx % dc);
  u32x2 o;
  if (c < sc) {
    f32x4 f = *(const f32x4*)(in + (size_t)r * sc + c);
    o[0] = (u32)f2bf(f[0]) | ((u32)f2bf(f[1]) << 16);
    o[1] = (u32)f2bf(f[2]) | ((u32)f2bf(f[3]) << 16);
  } else {
    o[0] = 0; o[1] = 0;
  }
  ((u32x2*)out)[i] = o;
}

// ---------------- prep: doc ranges + packed biases (Bqkv padded to H3P) ----------------
__global__ __launch_bounds__(256) void prep_k(const int* __restrict__ ids,
                                              const float* __restrict__ qb,
                                              const float* __restrict__ kb,
                                              const float* __restrict__ vb,
                                              const float* __restrict__ f1b,
                                              int* __restrict__ se,
                                              float* __restrict__ bqkv,
                                              float* __restrict__ bf1,
                                              float* __restrict__ zbuf) {
  int i = blockIdx.x * 256 + threadIdx.x;
  if (i < H3P)
    bqkv[i] = (i < HID) ? qb[i]
              : (i < 2 * HID) ? kb[i - HID]
              : (i < H3) ? vb[i - 2 * HID] : 0.f;
  if (i < FFP) bf1[i] = (i < FF) ? f1b[i] : 0.f;
  if (i < 16) zbuf[i] = 0.f;
  if (i < SEQ) {
    int id = ids[i];
    int lo = 0, hi = SEQ;
    while (lo < hi) { int mid = (lo + hi) >> 1; if (ids[mid] < id) lo = mid + 1; else hi = mid; }
    int s = lo;
    lo = 0; hi = SEQ;
    while (lo < hi) { int mid = (lo + hi) >> 1; if (ids[mid] <= id) lo = mid + 1; else hi = mid; }
    se[2 * i] = s;
    se[2 * i + 1] = lo;
  }
}

// ---------------- LayerNorm fp32 -> bf16 ----------------
__global__ __launch_bounds__(256) void ln_k(const float* __restrict__ x,
                                            const float* __restrict__ g,
                                            const float* __restrict__ b,
                                            u16* __restrict__ y) {
  __shared__ float sred[8];
  int row = blockIdx.x, tid = threadIdx.x;
  const f32x4* xr = (const f32x4*)(x + (size_t)row * HID);
  f32x4 v0 = {}, v1 = {};
  float s = 0.f, s2 = 0.f;
  int c0 = tid, c1 = tid + 256;
  v0 = xr[c0];
  if (c1 < 288) v1 = xr[c1];
#pragma unroll
  for (int j = 0; j < 4; ++j) { s += v0[j] + v1[j]; s2 += v0[j] * v0[j] + v1[j] * v1[j]; }
#pragma unroll
  for (int sh = 32; sh; sh >>= 1) { s += __shfl_xor(s, sh); s2 += __shfl_xor(s2, sh); }
  if ((tid & 63) == 0) { sred[tid >> 6] = s; sred[4 + (tid >> 6)] = s2; }
  __syncthreads();
  s = sred[0] + sred[1] + sred[2] + sred[3];
  s2 = sred[4] + sred[5] + sred[6] + sred[7];
  float mu = s * (1.f / HID);
  float rs = rsqrtf(s2 * (1.f / HID) - mu * mu + 1e-6f);
  u16* yr = y + (size_t)row * HID;
  const f32x4* g4 = (const f32x4*)g;
  const f32x4* b4 = (const f32x4*)b;
  {
    f32x4 gv = g4[c0], bv = b4[c0];
    u32x2 o;
    o[0] = (u32)f2bf((v0[0] - mu) * rs * gv[0] + bv[0]) |
           ((u32)f2bf((v0[1] - mu) * rs * gv[1] + bv[1]) << 16);
    o[1] = (u32)f2bf((v0[2] - mu) * rs * gv[2] + bv[2]) |
           ((u32)f2bf((v0[3] - mu) * rs * gv[3] + bv[3]) << 16);
    *(u32x2*)(yr + c0 * 4) = o;
  }
  if (c1 < 288) {
    f32x4 gv = g4[c1], bv = b4[c1];
    u32x2 o;
    o[0] = (u32)f2bf((v1[0] - mu) * rs * gv[0] + bv[0]) |
           ((u32)f2bf((v1[1] - mu) * rs * gv[1] + bv[1]) << 16);
    o[1] = (u32)f2bf((v1[2] - mu) * rs * gv[2] + bv[2]) |
           ((u32)f2bf((v1[3] - mu) * rs * gv[3] + bv[3]) << 16);
    *(u32x2*)(yr + c1 * 4) = o;
  }
}

// ---------------- 256x256 8-phase GEMM (m201 template port) ----------------
// 512 thr / 8 waves (2Mx4N), per-wave 128x64 out (8x4 frags), BK=64, dbuf LDS 128KB.
// Per K-tile kt, 4 phases: qd0 {issue A0(kt+1); vmcnt(6); bar; read 8 B-frags + 4 A-frags;
// 16 MFMA; bar}; qd1-3 {read 4 A-frags; issue A1(kt+1)/B0(kt+2)/B1(kt+2); bar; 16 MFMA; bar}.
// FIFO check (steady): outstanding at wait = 14 loads; vmcnt(6) retires A(kt)+B(kt). Tail vmcnt(0).
// Stage-overwrite safety: each region's last LDS read is >=1 barrier before its re-stage issue.
// T2 XOR both sides on 128B rows; T1 XCD swizzle; T5 setprio around MFMA.
// EP: 1 = bf16(gelu(acc+bias)) to [M][N]; 4 = bf16(acc+bias) head-major scatter, col<H3 guard.
template <int EP>
__global__ __launch_bounds__(512, 2) void gemm256(const u16* __restrict__ A,
                                                  const u16* __restrict__ B,
                                                  void* __restrict__ outp,
                                                  const float* __restrict__ bias,
                                                  int N, int K) {
  __shared__ u16 SM[65536];  // [op(2)][dbuf(2)][half(2)][128][64] bf16 = 128KB
  char* LDSB = (char*)SM;
  int tid = threadIdx.x;
  int l = tid & 63, w = tid >> 6;
  int wr = w >> 2, wc = w & 3;
  int gx = gridDim.x;
  int nxy = gx * gridDim.y;
  int bidf = blockIdx.y * gx + blockIdx.x;
  int cpx = nxy >> 3;
  bidf = (bidf & 7) * cpx + (bidf >> 3);
  int m0 = (bidf / gx) * 256, n0 = (bidf % gx) * 256;
  f32x4 acc[8][4] = {};
  // staging: thread t covers rows r0=t>>3 and r0+64 of a half, col chunk (t&7)*16 bytes,
  // source col pre-XORed with ((r0&7)<<4) (same for both rows; G21 both-sides)
  int r0 = tid >> 3;
  int cb = ((tid & 7) * 16) ^ ((r0 & 7) << 4);
  size_t rowstep = (size_t)K * 2;
  const char* Abase = (const char*)A + (size_t)(m0 + r0) * rowstep + cb;
  const char* Bbase = (const char*)B + (size_t)(n0 + r0) * rowstep + cb;
#define STAGE256(op_, kt_, half_)                                                        \
  {                                                                                      \
    char* dst_ = LDSB + ((op_)*2 + ((kt_)&1)) * 32768 + (half_)*16384 +                  \
                 (size_t)r0 * 128 + (size_t)((tid & 7) * 16);                            \
    const char* s_ = ((op_) ? Bbase : Abase) + (size_t)(half_) * 128 * rowstep +         \
                     (size_t)(kt_) * 128;                                                \
    load_lds16(s_, dst_);                                                                \
    load_lds16(s_ + 64 * rowstep, dst_ + 64 * 128);                                      \
  }
  // fragment read bases (byte): A region op0; B region op1 (+65536)
  const char* ArF = LDSB + wr * 16384 + (size_t)(l & 15) * 128;
  const char* BrF = LDSB + 65536 + (wc >> 1) * 16384 + (size_t)((wc & 1) * 64 + (l & 15)) * 128;
  int cs0 = ((l >> 4) * 16) ^ ((l & 7) << 4);
  int cs1 = cs0 ^ 64;
  int nkt = K / 64;  // 18
  // prologue: A0(0) A1(0) B0(0) B1(0) B0(1) B1(1)
  STAGE256(0, 0, 0); STAGE256(0, 0, 1);
  STAGE256(1, 0, 0); STAGE256(1, 0, 1);
  STAGE256(1, 1, 0); STAGE256(1, 1, 1);
  for (int kt = 0; kt < nkt; ++kt) {
    int db = kt & 1;
    const char* Ar = ArF + db * 32768;
    const char* Br = BrF + db * 32768;
    bf16x8 bfr[4][2];
#pragma unroll
    for (int qd = 0; qd < 4; ++qd) {
      bf16x8 af[2][2];
      if (qd == 0) {
        if (kt + 1 < nkt) STAGE256(0, kt + 1, 0);
        if (kt == nkt - 1) {
          asm volatile("s_waitcnt vmcnt(0)" ::: "memory");
        } else {
          asm volatile("s_waitcnt vmcnt(6)" ::: "memory");
        }
        __builtin_amdgcn_sched_barrier(0);
        __builtin_amdgcn_s_barrier();
        __builtin_amdgcn_sched_barrier(0);
#pragma unroll
        for (int n = 0; n < 4; ++n) {
          bfr[n][0] = *(const bf16x8*)(Br + n * 2048 + cs0);
          bfr[n][1] = *(const bf16x8*)(Br + n * 2048 + cs1);
        }
#pragma unroll
        for (int i = 0; i < 2; ++i) {
          af[i][0] = *(const bf16x8*)(Ar + (0 * 2 + i) * 2048 + cs0);
          af[i][1] = *(const bf16x8*)(Ar + (0 * 2 + i) * 2048 + cs1);
        }
      } else {
#pragma unroll
        for (int i = 0; i < 2; ++i) {
          af[i][0] = *(const bf16x8*)(Ar + (qd * 2 + i) * 2048 + cs0);
          af[i][1] = *(const bf16x8*)(Ar + (qd * 2 + i) * 2048 + cs1);
        }
        if (qd == 1) { if (kt + 1 < nkt) STAGE256(0, kt + 1, 1); }
        if (qd == 2) { if (kt + 2 < nkt) STAGE256(1, kt + 2, 0); }
        if (qd == 3) { if (kt + 2 < nkt) STAGE256(1, kt + 2, 1); }
        __builtin_amdgcn_sched_barrier(0);
        __builtin_amdgcn_s_barrier();
        __builtin_amdgcn_sched_barrier(0);
      }
      __builtin_amdgcn_s_setprio(1);
#pragma unroll
      for (int i = 0; i < 2; ++i)
#pragma unroll
        for (int n = 0; n < 4; ++n) {
          acc[qd * 2 + i][n] =
              __builtin_amdgcn_mfma_f32_16x16x32_bf16(af[i][0], bfr[n][0], acc[qd * 2 + i][n], 0, 0, 0);
          acc[qd * 2 + i][n] =
              __builtin_amdgcn_mfma_f32_16x16x32_bf16(af[i][1], bfr[n][1], acc[qd * 2 + i][n], 0, 0, 0);
        }
      __builtin_amdgcn_s_setprio(0);
      __builtin_amdgcn_sched_barrier(0);
      __builtin_amdgcn_s_barrier();
      __builtin_amdgcn_sched_barrier(0);
    }
  }
#undef STAGE256
  // epilogue
#pragma unroll
  for (int m = 0; m < 8; ++m) {
    int row = m0 + wr * 128 + m * 16 + (l >> 4) * 4;
#pragma unroll
    for (int n = 0; n < 4; ++n) {
      int col = n0 + wc * 64 + n * 16 + (l & 15);
      if (EP == 4) {
        if (col < H3) {
          float bv = bias[col];
          int region = (col >= 2304) ? 2 : (col >= 1152 ? 1 : 0);
          int cw = col - region * 1152;
          int hh = cw / 72;
          int dd = cw - hh * 72;
          u16* dst = (u16*)outp + (((size_t)region * NHEAD + hh) * SEQ) * HDIM + dd;
#pragma unroll
          for (int j = 0; j < 4; ++j)
            dst[(size_t)(row + j) * HDIM] = f2bf(acc[m][n][j] + bv);
        }
      } else {
        float bv = bias[col];
#pragma unroll
        for (int j = 0; j < 4; ++j)
          ((u16*)outp)[(size_t)(row + j) * N + col] = f2bf(gelu_fast(acc[m][n][j] + bv));
      }
    }
  }
}

// ---------------- 128x128 ring-5 GEMM (r12, kept for O-proj + FC2 splitK) ----------------
// EP: 2 = f32(acc+bias+resid); 5 = split-K partial bf16
template <int EP>
__global__ __launch_bounds__(256, 2) void gemm_bt(const u16* __restrict__ A,
                                                  const u16* __restrict__ B,
                                                  void* __restrict__ outp,
                                                  const float* __restrict__ bias,
                                                  const float* __restrict__ resid,
                                                  int M, int N, int K) {
  __shared__ u16 As[5 * 128 * 32];
  __shared__ u16 Bs[5 * 128 * 32];
  int tid = threadIdx.x;
  int l = tid & 63, w = tid >> 6;
  int nxy = gridDim.x * gridDim.y;
  int bidf = blockIdx.y * gridDim.x + blockIdx.x;
  int cpx = nxy >> 3;
  bidf = (bidf & 7) * cpx + (bidf >> 3);
  int m0 = (bidf / gridDim.x) * 128;
  int n0 = (bidf % gridDim.x) * 128;
  int wr = w >> 1, wc = w & 1;
  f32x4 acc[4][4] = {};
  int sr = tid >> 2, sc = tid & 3;
  int row0 = sr, row1 = 64 + sr;
  int x0 = ((row0 >> 1) & 3) ^ (((row0 >> 3) & 1) << 1);
  int x1 = ((row1 >> 1) & 3) ^ (((row1 >> 3) & 1) << 1);
  const char* Ag0 = (const char*)A + ((size_t)(m0 + row0) * K + (size_t)((sc ^ x0) * 8)) * 2;
  const char* Ag1 = (const char*)A + ((size_t)(m0 + row1) * K + (size_t)((sc ^ x1) * 8)) * 2;
  const char* Bg0 = (const char*)B + ((size_t)(n0 + row0) * K + (size_t)((sc ^ x0) * 8)) * 2;
  const char* Bg1 = (const char*)B + ((size_t)(n0 + row1) * K + (size_t)((sc ^ x1) * 8)) * 2;
  char* AsB = (char*)As;
  char* BsB = (char*)Bs;
  int xl = (((l & 15) >> 1) & 3) ^ ((((l & 15) >> 3) & 1) << 1);
  int cfr = ((l >> 4) ^ xl) * 16;
  const char* ArB = (const char*)As + (wr * 64 + (l & 15)) * 64 + cfr;
  const char* BrB = (const char*)Bs + (wc * 64 + (l & 15)) * 64 + cfr;
  int k0 = 0, kend = K;
  if (EP == 5) {
    int nz = gridDim.z;
    int ksp = ((K / 32 + nz - 1) / nz) * 32;
    k0 = blockIdx.z * ksp;
    kend = min(K, k0 + ksp);
  }
  int nsteps = (kend - k0) / 32;
#pragma unroll
  for (int tt = 0; tt < 3; ++tt) {
    size_t kb = (size_t)(k0 + tt * 32) * 2;
    char* sa = AsB + tt * 8192;
    char* sb = BsB + tt * 8192;
    load_lds16(Ag0 + kb, sa + tid * 16);
    load_lds16(Ag1 + kb, sa + 4096 + tid * 16);
    load_lds16(Bg0 + kb, sb + tid * 16);
    load_lds16(Bg1 + kb, sb + 4096 + tid * 16);
  }
  int buf = 0;
  for (int t = 0; t < nsteps; ++t) {
    if (t + 3 < nsteps) {
      int nb = buf + 3;
      if (nb >= 5) nb -= 5;
      size_t kb = (size_t)(k0 + (t + 3) * 32) * 2;
      char* sa = AsB + nb * 8192;
      char* sb = BsB + nb * 8192;
      load_lds16(Ag0 + kb, sa + tid * 16);
      load_lds16(Ag1 + kb, sa + 4096 + tid * 16);
      load_lds16(Bg0 + kb, sb + tid * 16);
      load_lds16(Bg1 + kb, sb + 4096 + tid * 16);
      asm volatile("s_waitcnt vmcnt(8)" ::: "memory");
    } else {
      asm volatile("s_waitcnt vmcnt(0)" ::: "memory");
    }
    __builtin_amdgcn_sched_barrier(0);
    __builtin_amdgcn_s_barrier();
    __builtin_amdgcn_sched_barrier(0);
    {
      const char* Ar = ArB + buf * 8192;
      const char* Br = BrB + buf * 8192;
      bf16x8 af[4], bfr[4];
#pragma unroll
      for (int m = 0; m < 4; ++m) af[m] = *(const bf16x8*)(Ar + m * 1024);
#pragma unroll
      for (int n = 0; n < 4; ++n) bfr[n] = *(const bf16x8*)(Br + n * 1024);
      __builtin_amdgcn_s_setprio(1);
#pragma unroll
      for (int m = 0; m < 4; ++m)
#pragma unroll
        for (int n = 0; n < 4; ++n)
          acc[m][n] = __builtin_amdgcn_mfma_f32_16x16x32_bf16(af[m], bfr[n], acc[m][n], 0, 0, 0);
      __builtin_amdgcn_s_setprio(0);
    }
    __builtin_amdgcn_sched_barrier(0);
    buf = buf == 4 ? 0 : buf + 1;
  }
#pragma unroll
  for (int m = 0; m < 4; ++m) {
    int row = m0 + wr * 64 + m * 16 + (l >> 4) * 4;
#pragma unroll
    for (int n = 0; n < 4; ++n) {
      int col = n0 + wc * 64 + n * 16 + (l & 15);
      if (EP == 5) {
        u16* P = (u16*)outp + (size_t)blockIdx.z * M * N;
#pragma unroll
        for (int j = 0; j < 4; ++j)
          P[(size_t)(row + j) * N + col] = f2bf(acc[m][n][j]);
      } else {
        float bv = bias[col];
#pragma unroll
        for (int j = 0; j < 4; ++j) {
          size_t idx = (size_t)(row + j) * N + col;
          ((float*)outp)[idx] = acc[m][n][j] + bv + resid[idx];
        }
      }
    }
  }
}

// ---------------- split-K reduce ----------------
template <int NS>
__global__ __launch_bounds__(256) void splitk_reduce_k(const u16* __restrict__ P,
                                                       const float* __restrict__ bias,
                                                       const float* __restrict__ resid,
                                                       float* __restrict__ out, int n4) {
  int i = blockIdx.x * 256 + threadIdx.x;
  if (i >= n4) return;
  size_t base = (size_t)i * 4;
  int col = (int)(base % HID);
  f32x4 a = {};
#pragma unroll
  for (int s = 0; s < NS; ++s) {
    u32x2 pv = *(const u32x2*)(P + (size_t)s * SEQ * HID + base);
    a[0] += bflo(pv[0]);
    a[1] += bfhi(pv[0]);
    a[2] += bflo(pv[1]);
    a[3] += bfhi(pv[1]);
  }
  f32x4 bv = *(const f32x4*)(bias + col);
  f32x4 rv = ((const f32x4*)resid)[i];
  ((f32x4*)out)[i] = a + bv + rv;
}

// ---------------- document-masked attention (unchanged) ----------------
__device__ __forceinline__ u32 swz(u32 a) { return a ^ (((a >> 8) & 7u) << 4); }

__global__ __launch_bounds__(256, 2) void attn_mfma_k(const u16* __restrict__ qkvh,
                                                      const int* __restrict__ se,
                                                      const float* __restrict__ zb,
                                                      u16* __restrict__ outb) {
  __shared__ u16 Ks[128 * 104];
  __shared__ u16 Vt[80 * 128];
  __shared__ u16 Ps[4][16 * 128];
  __shared__ int Sq[64], Eq[64];
  int tid = threadIdx.x, l = tid & 63, w = tid >> 6;
  int h = blockIdx.y, q0 = blockIdx.x * 64;
  const float scale = 0.1178511302f;
  const u16* Qh = qkvh + (size_t)h * SEQ * HDIM;
  const u16* Kh = qkvh + ((size_t)NHEAD + h) * SEQ * HDIM;
  const u16* Vh = qkvh + ((size_t)2 * NHEAD + h) * SEQ * HDIM;

  for (int i = tid; i < 512; i += 256) ((u32*)(Vt + 72 * 128))[i] = 0;

#pragma unroll
  for (int it = 0; it < 4; ++it) {
    int cw0 = it * 256 + w * 64;
    if (cw0 < 832) {
      int chunk = cw0 + l;
      int row = chunk / 13, c16 = chunk - row * 13;
      const void* src = (c16 < 9)
                            ? (const void*)(Qh + ((size_t)(q0 + row)) * HDIM + c16 * 8)
                            : (const void*)zb;
      load_lds16(src, (char*)Ks + (size_t)cw0 * 16);
    }
  }
  if (tid < 64) { Sq[tid] = se[2 * (q0 + tid)]; Eq[tid] = se[2 * (q0 + tid) + 1]; }
  __syncthreads();

  int sqj[4], eqj[4];
#pragma unroll
  for (int j = 0; j < 4; ++j) {
    int ql = w * 16 + (l >> 4) * 4 + j;
    sqj[j] = Sq[ql]; eqj[j] = Eq[ql];
  }
  const char* Aq = (const char*)Ks + (w * 16 + (l & 15)) * 208 + (l >> 4) * 16;
  bf16x8 aq[3];
#pragma unroll
  for (int dsl = 0; dsl < 3; ++dsl) aq[dsl] = *(const bf16x8*)(Aq + dsl * 64);
  __syncthreads();

  int kmin = se[2 * q0];
  int kmax = se[2 * (q0 + 63) + 1];
  f32x4 o[5] = {};
  float m_run[4], l_run[4];
#pragma unroll
  for (int j = 0; j < 4; ++j) { m_run[j] = -1e30f; l_run[j] = 0.f; }

  for (int kc = kmin; kc < kmax; kc += 128) {
#pragma unroll
    for (int it = 0; it < 7; ++it) {
      int cw0 = it * 256 + w * 64;
      if (cw0 < 1664) {
        int chunk = cw0 + l;
        int row = chunk / 13, c16 = chunk - row * 13;
        int krow = kc + row;
        const void* src = (c16 < 9 && krow < SEQ)
                              ? (const void*)(Kh + (size_t)krow * HDIM + c16 * 8)
                              : (const void*)zb;
        load_lds16(src, (char*)Ks + (size_t)cw0 * 16);
      }
    }
#pragma unroll
    for (int it = 0; it < 3; ++it) {
      int idx = it * 256 + tid;
      if (idx < 576) {
        int k2 = idx / 9, d8 = idx - k2 * 9;
        int kr0 = kc + 2 * k2, kr1 = kr0 + 1;
        kr0 = kr0 < SEQ ? kr0 : SEQ - 1;
        kr1 = kr1 < SEQ ? kr1 : SEQ - 1;
        u16x8 r0 = *(const u16x8*)(Vh + (size_t)kr0 * HDIM + d8 * 8);
        u16x8 r1 = *(const u16x8*)(Vh + (size_t)kr1 * HDIM + d8 * 8);
#pragma unroll
        for (int j = 0; j < 8; ++j) {
          u32 pr = (u32)r0[j] | ((u32)r1[j] << 16);
          *(u32*)((char*)Vt + swz((u32)(d8 * 8 + j) * 256 + (u32)k2 * 4)) = pr;
        }
      }
    }
    __syncthreads();

    f32x4 sf[8];
#pragma unroll
    for (int kt = 0; kt < 8; ++kt) {
      const char* Bk = (const char*)Ks + (kt * 16 + (l & 15)) * 208 + (l >> 4) * 16;
      f32x4 acc = {};
      acc = __builtin_amdgcn_mfma_f32_16x16x32_bf16(aq[0], *(const bf16x8*)Bk, acc, 0, 0, 0);
      acc = __builtin_amdgcn_mfma_f32_16x16x32_bf16(aq[1], *(const bf16x8*)(Bk + 64), acc, 0, 0, 0);
      acc = __builtin_amdgcn_mfma_f32_16x16x32_bf16(aq[2], *(const bf16x8*)(Bk + 128), acc, 0, 0, 0);
      sf[kt] = acc;
    }
    float mx[4] = {-1e30f, -1e30f, -1e30f, -1e30f};
#pragma unroll
    for (int kt = 0; kt < 8; ++kt) {
      int key = kc + kt * 16 + (l & 15);
#pragma unroll
      for (int j = 0; j < 4; ++j) {
        float s = sf[kt][j] * scale;
        bool valid = (key >= sqj[j]) && (key < eqj[j]);
        s = valid ? s : -1e30f;
        sf[kt][j] = s;
        mx[j] = fmaxf(mx[j], s);
      }
    }
#pragma unroll
    for (int j = 0; j < 4; ++j) {
      float m = mx[j];
      m = fmaxf(m, __shfl_xor(m, 1));
      m = fmaxf(m, __shfl_xor(m, 2));
      m = fmaxf(m, __shfl_xor(m, 4));
      m = fmaxf(m, __shfl_xor(m, 8));
      mx[j] = m;
    }
    float fz[4], ps[4];
#pragma unroll
    for (int j = 0; j < 4; ++j) {
      float mn = fmaxf(m_run[j], mx[j]);
      fz[j] = __expf(m_run[j] - mn);
      m_run[j] = mn;
      ps[j] = 0.f;
    }
#pragma unroll
    for (int kt = 0; kt < 8; ++kt)
#pragma unroll
      for (int j = 0; j < 4; ++j) {
        float s = sf[kt][j];
        float p = (s > -1e29f) ? __expf(s - m_run[j]) : 0.f;
        sf[kt][j] = p;
        ps[j] += p;
      }
#pragma unroll
    for (int j = 0; j < 4; ++j) {
      float p = ps[j];
      p += __shfl_xor(p, 1);
      p += __shfl_xor(p, 2);
      p += __shfl_xor(p, 4);
      p += __shfl_xor(p, 8);
      l_run[j] = l_run[j] * fz[j] + p;
#pragma unroll
      for (int dt = 0; dt < 5; ++dt) o[dt][j] *= fz[j];
    }
    char* PB = (char*)Ps[w];
#pragma unroll
    for (int kt = 0; kt < 8; ++kt)
#pragma unroll
      for (int j = 0; j < 4; ++j) {
        u32 a = (u32)((l >> 4) * 4 + j) * 256 + (u32)(kt * 16 + (l & 15)) * 2;
        *(u16*)(PB + swz(a)) = f2bf(sf[kt][j]);
      }
#pragma unroll
    for (int ks = 0; ks < 4; ++ks) {
      u32 aa = (u32)(l & 15) * 256 + (u32)((l >> 4) * 8 + ks * 32) * 2;
      bf16x8 ap = *(const bf16x8*)(PB + swz(aa));
#pragma unroll
      for (int dt = 0; dt < 5; ++dt) {
        u32 ba = (u32)(dt * 16 + (l & 15)) * 256 + (u32)((l >> 4) * 8 + ks * 32) * 2;
        bf16x8 bv = *(const bf16x8*)((const char*)Vt + swz(ba));
        o[dt] = __builtin_amdgcn_mfma_f32_16x16x32_bf16(ap, bv, o[dt], 0, 0, 0);
      }
    }
    __syncthreads();
  }

  float inv[4];
#pragma unroll
  for (int j = 0; j < 4; ++j) inv[j] = 1.f / l_run[j];
#pragma unroll
  for (int dt = 0; dt < 5; ++dt) {
    int d = dt * 16 + (l & 15);
    if (d < HDIM) {
#pragma unroll
      for (int j = 0; j < 4; ++j) {
        int q = q0 + w * 16 + (l >> 4) * 4 + j;
        outb[(size_t)q * HID + h * HDIM + d] = f2bf(o[dt][j] * inv[j]);
      }
    }
  }
}

// ---------------- workspace layout ----------------
constexpr size_t SZ_WQKV = (size_t)H3 * HID * 2;
constexpr size_t SZ_WO   = (size_t)HID * HID * 2;
constexpr size_t SZ_WF1  = (size_t)FFP * HID * 2;
constexpr size_t SZ_WF2  = (size_t)HID * FFP * 2;
constexpr size_t OFF_WQKV = 0;
constexpr size_t OFF_WO   = OFF_WQKV + SZ_WQKV;  // contiguous: QKV pad rows alias Wo (finite)
constexpr size_t OFF_WF1  = OFF_WO + SZ_WO;
constexpr size_t OFF_BQKV = OFF_WF1 + SZ_WF1;
constexpr size_t OFF_BF1  = OFF_BQKV + (size_t)H3P * 4;
constexpr size_t OFF_SE   = OFF_BF1 + (size_t)FFP * 4;
constexpr size_t OFF_ZB   = OFF_SE + (size_t)SEQ * 2 * 4;
constexpr size_t OFF_XLN  = OFF_ZB + 64;
constexpr size_t OFF_QKV  = OFF_XLN + (size_t)SEQ * HID * 2;
constexpr size_t OFF_ACT  = OFF_QKV;  // ACT overlays QKV+AOUT (dead by FC1)
constexpr size_t OFF_AOUT = OFF_QKV + (size_t)SEQ * H3 * 2;
constexpr size_t OFF_HD   = OFF_AOUT + (size_t)SEQ * HID * 2;
constexpr size_t OFF_WF2  = OFF_HD + (size_t)SEQ * HID * 4;
constexpr size_t WS_NEED  = OFF_WF2 + SZ_WF2;
constexpr size_t OFF_P    = 0;  // split-K partials overlay dead prefix
static_assert(OFF_ACT + (size_t)SEQ * FFP * 2 <= OFF_HD, "ACT must not clobber HD");
static_assert(3 * (size_t)SEQ * HID * 2 <= OFF_QKV, "P must stay in dead prefix");

extern "C" void kernel_launch(void* const* d_in, const int* in_sizes, int n_in,
                              void* d_out, int out_size, void* d_ws, size_t ws_size,
                              hipStream_t stream) {
  const float* hs   = (const float*)d_in[0];
  const int*   ids  = (const int*)d_in[1];
  const float* q_w  = (const float*)d_in[2];
  const float* q_b  = (const float*)d_in[3];
  const float* k_w  = (const float*)d_in[4];
  const float* k_b  = (const float*)d_in[5];
  const float* v_w  = (const float*)d_in[6];
  const float* v_b  = (const float*)d_in[7];
  const float* o_w  = (const float*)d_in[8];
  const float* o_b  = (const float*)d_in[9];
  const float* ln1g = (const float*)d_in[10];
  const float* ln1b = (const float*)d_in[11];
  const float* ln2g = (const float*)d_in[12];
  const float* ln2b = (const float*)d_in[13];
  const float* f1w  = (const float*)d_in[14];
  const float* f1b  = (const float*)d_in[15];
  const float* f2w  = (const float*)d_in[16];
  const float* f2b  = (const float*)d_in[17];

  if (ws_size < WS_NEED) return;

  char* ws = (char*)d_ws;
  u16*   Wqkv = (u16*)(ws + OFF_WQKV);
  u16*   Wo   = (u16*)(ws + OFF_WO);
  u16*   Wf1  = (u16*)(ws + OFF_WF1);
  u16*   Wf2  = (u16*)(ws + OFF_WF2);
  float* Bqkv = (float*)(ws + OFF_BQKV);
  float* Bf1  = (float*)(ws + OFF_BF1);
  int*   SE   = (int*)(ws + OFF_SE);
  float* ZB   = (float*)(ws + OFF_ZB);
  u16*   XLN  = (u16*)(ws + OFF_XLN);
  u16*   QKVh = (u16*)(ws + OFF_QKV);
  u16*   ACT  = (u16*)(ws + OFF_ACT);
  u16*   AOUT = (u16*)(ws + OFF_AOUT);
  float* HD   = (float*)(ws + OFF_HD);
  u16*   Pp   = (u16*)(ws + OFF_P);

  prep_k<<<dim3((FFP + 255) / 256), dim3(256), 0, stream>>>(ids, q_b, k_b, v_b, f1b, SE, Bqkv,
                                                            Bf1, ZB);
  int nW = HID * HID;
  cvt4x4_k<<<dim3(nW / 4 / 256, 4), dim3(256), 0, stream>>>(q_w, k_w, v_w, o_w, Wqkv, nW / 4);
  {
    int n4 = FFP * HID / 4;
    cvt4_pad_k<<<dim3((n4 + 255) / 256), dim3(256), 0, stream>>>(f1w, Wf1, 1, FF * HID, FFP * HID);
  }
  {
    int n4 = HID * FFP / 4;
    cvt4_pad_k<<<dim3((n4 + 255) / 256), dim3(256), 0, stream>>>(f2w, Wf2, HID, FF, FFP);
  }

  // LN1
  ln_k<<<dim3(SEQ), dim3(256), 0, stream>>>(hs, ln1g, ln1b, XLN);
  // QKV projection (8-phase 256^2, logical N=3584, stores guarded col<3456)
  gemm256<4><<<dim3(H3P / 256, SEQ / 256), dim3(512), 0, stream>>>(XLN, Wqkv, QKVh, Bqkv,
                                                                   H3P, HID);
  // doc-masked attention
  attn_mfma_k<<<dim3(SEQ / 64, NHEAD), dim3(256), 0, stream>>>(QKVh, SE, ZB, AOUT);
  // O projection + residual (ring-5 128^2)
  gemm_bt<2><<<dim3(HID / 128, SEQ / 128), dim3(256), 0, stream>>>(AOUT, Wo, HD, o_b, hs,
                                                                   SEQ, HID, HID);
  // LN2
  ln_k<<<dim3(SEQ), dim3(256), 0, stream>>>(HD, ln2g, ln2b, XLN);
  // FC1 + GELU (8-phase 256^2)
  gemm256<1><<<dim3(FFP / 256, SEQ / 256), dim3(512), 0, stream>>>(XLN, Wf1, ACT, Bf1,
                                                                   FFP, HID);
  // FC2 split-K=3 partials (ring-5)
  gemm_bt<5><<<dim3(HID / 128, SEQ / 128, 3), dim3(256), 0, stream>>>(ACT, Wf2, Pp, nullptr,
                                                                      nullptr, SEQ, HID, FFP);
  // reduce + bias + residual -> fp32 output
  splitk_reduce_k<3><<<dim3(SEQ * HID / 4 / 256), dim3(256), 0, stream>>>(Pp, f2b, HD,
                                                                          (float*)d_out,
                                                                          SEQ * HID / 4);
}

// Round 14
// 285.535 us; speedup vs baseline: 1.0140x; 1.0140x over previous
//
#include <hip/hip_runtime.h>

typedef unsigned short u16;
typedef unsigned int u32;
typedef __attribute__((ext_vector_type(8))) __bf16 bf16x8;
typedef __attribute__((ext_vector_type(8))) u16 u16x8;
typedef __attribute__((ext_vector_type(4))) float f32x4;
typedef __attribute__((ext_vector_type(2))) u32 u32x2;

#define SEQ 4096
#define HID 1152
#define NHEAD 16
#define HDIM 72
#define FF 4304
#define FFP 4352
#define H3 3456

__device__ __forceinline__ u16 f2bf(float f) {
  u32 u = __builtin_bit_cast(u32, f);
  u32 r = u + 0x7fffu + ((u >> 16) & 1u);
  return (u16)(r >> 16);
}
__device__ __forceinline__ float bf2f(u16 h) {
  return __builtin_bit_cast(float, (u32)h << 16);
}
__device__ __forceinline__ float bflo(u32 u) { return __builtin_bit_cast(float, u << 16); }
__device__ __forceinline__ float bfhi(u32 u) { return __builtin_bit_cast(float, u & 0xffff0000u); }

typedef const __attribute__((address_space(1))) void* gas_t;
typedef __attribute__((address_space(3))) void* las_t;
__device__ __forceinline__ void load_lds16(const void* g, void* l) {
  __builtin_amdgcn_global_load_lds((gas_t)(unsigned long long)g,
                                   (las_t)(u32)(unsigned long long)l, 16, 0, 0);
}

__device__ __forceinline__ float gelu_fast(float x) {
  float z = 0.7978845608f * (x + 0.044715f * x * x * x);
  return x / (1.f + __expf(-2.f * z));
}

// ---------------- merged weight converts (one launch, 6 segments) ----------------
// seg 0-3: q/k/v/o [HID*HID] -> Wqkv (contiguous, Wo = +3*HID*HID)
// seg 4: FC1 flat pad [FF*HID] -> [FFP*HID]
// seg 5: FC2 row pad  [HID][FF] -> [HID][FFP]
__global__ __launch_bounds__(256) void cvt_all_k(const float* __restrict__ qw,
                                                 const float* __restrict__ kw,
                                                 const float* __restrict__ vw,
                                                 const float* __restrict__ ow,
                                                 const float* __restrict__ f1w,
                                                 const float* __restrict__ f2w,
                                                 u16* __restrict__ wqkv,
                                                 u16* __restrict__ wf1,
                                                 u16* __restrict__ wf2) {
  int seg = blockIdx.y;
  int i = blockIdx.x * 256 + threadIdx.x;
  u32x2 o;
  if (seg < 4) {
    int n4 = HID * HID / 4;
    if (i >= n4) return;
    const float* in = (seg == 0) ? qw : (seg == 1) ? kw : (seg == 2) ? vw : ow;
    f32x4 f = ((const f32x4*)in)[i];
    o[0] = (u32)f2bf(f[0]) | ((u32)f2bf(f[1]) << 16);
    o[1] = (u32)f2bf(f[2]) | ((u32)f2bf(f[3]) << 16);
    ((u32x2*)(wqkv + (size_t)seg * HID * HID))[i] = o;
  } else if (seg == 4) {
    int n4 = FFP * HID / 4;
    if (i >= n4) return;
    int c = i * 4;
    if (c < FF * HID) {
      f32x4 f = *(const f32x4*)(f1w + c);
      o[0] = (u32)f2bf(f[0]) | ((u32)f2bf(f[1]) << 16);
      o[1] = (u32)f2bf(f[2]) | ((u32)f2bf(f[3]) << 16);
    } else {
      o[0] = 0; o[1] = 0;
    }
    ((u32x2*)wf1)[i] = o;
  } else {
    int n4 = HID * FFP / 4;
    if (i >= n4) return;
    int idx = i * 4;
    int r = idx / FFP;
    int c = idx - r * FFP;
    if (c < FF) {
      f32x4 f = *(const f32x4*)(f2w + (size_t)r * FF + c);
      o[0] = (u32)f2bf(f[0]) | ((u32)f2bf(f[1]) << 16);
      o[1] = (u32)f2bf(f[2]) | ((u32)f2bf(f[3]) << 16);
    } else {
      o[0] = 0; o[1] = 0;
    }
    ((u32x2*)wf2)[i] = o;
  }
}

// ---------------- prep: doc ranges + packed biases + zero buf ----------------
__global__ __launch_bounds__(256) void prep_k(const int* __restrict__ ids,
                                              const float* __restrict__ qb,
                                              const float* __restrict__ kb,
                                              const float* __restrict__ vb,
                                              const float* __restrict__ f1b,
                                              int* __restrict__ se,
                                              float* __restrict__ bqkv,
                                              float* __restrict__ bf1,
                                              float* __restrict__ zbuf) {
  int i = blockIdx.x * 256 + threadIdx.x;
  if (i < H3) bqkv[i] = (i < HID) ? qb[i] : (i < 2 * HID ? kb[i - HID] : vb[i - 2 * HID]);
  if (i < FFP) bf1[i] = (i < FF) ? f1b[i] : 0.f;
  if (i < 16) zbuf[i] = 0.f;
  if (i < SEQ) {
    int id = ids[i];
    int lo = 0, hi = SEQ;
    while (lo < hi) { int mid = (lo + hi) >> 1; if (ids[mid] < id) lo = mid + 1; else hi = mid; }
    int s = lo;
    lo = 0; hi = SEQ;
    while (lo < hi) { int mid = (lo + hi) >> 1; if (ids[mid] <= id) lo = mid + 1; else hi = mid; }
    se[2 * i] = s;
    se[2 * i + 1] = lo;
  }
}

// ---------------- LayerNorm fp32 -> bf16 ----------------
__global__ __launch_bounds__(256) void ln_k(const float* __restrict__ x,
                                            const float* __restrict__ g,
                                            const float* __restrict__ b,
                                            u16* __restrict__ y) {
  __shared__ float sred[8];
  int row = blockIdx.x, tid = threadIdx.x;
  const f32x4* xr = (const f32x4*)(x + (size_t)row * HID);
  f32x4 v0 = {}, v1 = {};
  float s = 0.f, s2 = 0.f;
  int c0 = tid, c1 = tid + 256;
  v0 = xr[c0];
  if (c1 < 288) v1 = xr[c1];
#pragma unroll
  for (int j = 0; j < 4; ++j) { s += v0[j] + v1[j]; s2 += v0[j] * v0[j] + v1[j] * v1[j]; }
#pragma unroll
  for (int sh = 32; sh; sh >>= 1) { s += __shfl_xor(s, sh); s2 += __shfl_xor(s2, sh); }
  if ((tid & 63) == 0) { sred[tid >> 6] = s; sred[4 + (tid >> 6)] = s2; }
  __syncthreads();
  s = sred[0] + sred[1] + sred[2] + sred[3];
  s2 = sred[4] + sred[5] + sred[6] + sred[7];
  float mu = s * (1.f / HID);
  float rs = rsqrtf(s2 * (1.f / HID) - mu * mu + 1e-6f);
  u16* yr = y + (size_t)row * HID;
  const f32x4* g4 = (const f32x4*)g;
  const f32x4* b4 = (const f32x4*)b;
  {
    f32x4 gv = g4[c0], bv = b4[c0];
    u32x2 o;
    o[0] = (u32)f2bf((v0[0] - mu) * rs * gv[0] + bv[0]) |
           ((u32)f2bf((v0[1] - mu) * rs * gv[1] + bv[1]) << 16);
    o[1] = (u32)f2bf((v0[2] - mu) * rs * gv[2] + bv[2]) |
           ((u32)f2bf((v0[3] - mu) * rs * gv[3] + bv[3]) << 16);
    *(u32x2*)(yr + c0 * 4) = o;
  }
  if (c1 < 288) {
    f32x4 gv = g4[c1], bv = b4[c1];
    u32x2 o;
    o[0] = (u32)f2bf((v1[0] - mu) * rs * gv[0] + bv[0]) |
           ((u32)f2bf((v1[1] - mu) * rs * gv[1] + bv[1]) << 16);
    o[1] = (u32)f2bf((v1[2] - mu) * rs * gv[2] + bv[2]) |
           ((u32)f2bf((v1[3] - mu) * rs * gv[3] + bv[3]) << 16);
    *(u32x2*)(yr + c1 * 4) = o;
  }
}

// ---------------- GEMM: C[M,N] = A[M,K] @ B[N,K]^T (r10-best: ring-3, BK=32) ----------------
// EP: 1 = bf16(gelu(acc+bias)); 2 = f32(acc+bias+resid);
// EP: 4 = bf16(acc+bias) scattered head-major QKV; EP: 5 = split-K partial bf16
template <int EP>
__global__ __launch_bounds__(256, 3) void gemm_bt(const u16* __restrict__ A,
                                                  const u16* __restrict__ B,
                                                  void* __restrict__ outp,
                                                  const float* __restrict__ bias,
                                                  const float* __restrict__ resid,
                                                  int M, int N, int K) {
  __shared__ u16 As[3 * 128 * 32];
  __shared__ u16 Bs[3 * 128 * 32];
  int tid = threadIdx.x;
  int l = tid & 63, w = tid >> 6;
  int nxy = gridDim.x * gridDim.y;
  int bidf = blockIdx.y * gridDim.x + blockIdx.x;
  int cpx = nxy >> 3;
  bidf = (bidf & 7) * cpx + (bidf >> 3);
  int m0 = (bidf / gridDim.x) * 128;
  int n0 = (bidf % gridDim.x) * 128;
  int wr = w >> 1, wc = w & 1;
  f32x4 acc[4][4] = {};
  int sr = tid >> 2, sc = tid & 3;
  int row0 = sr, row1 = 64 + sr;
  int x0 = ((row0 >> 1) & 3) ^ (((row0 >> 3) & 1) << 1);
  int x1 = ((row1 >> 1) & 3) ^ (((row1 >> 3) & 1) << 1);
  const char* Ag0 = (const char*)A + ((size_t)(m0 + row0) * K + (size_t)((sc ^ x0) * 8)) * 2;
  const char* Ag1 = (const char*)A + ((size_t)(m0 + row1) * K + (size_t)((sc ^ x1) * 8)) * 2;
  const char* Bg0 = (const char*)B + ((size_t)(n0 + row0) * K + (size_t)((sc ^ x0) * 8)) * 2;
  const char* Bg1 = (const char*)B + ((size_t)(n0 + row1) * K + (size_t)((sc ^ x1) * 8)) * 2;
  char* AsB = (char*)As;
  char* BsB = (char*)Bs;
  int xl = (((l & 15) >> 1) & 3) ^ ((((l & 15) >> 3) & 1) << 1);
  int cfr = ((l >> 4) ^ xl) * 16;
  const char* ArB = (const char*)As + (wr * 64 + (l & 15)) * 64 + cfr;
  const char* BrB = (const char*)Bs + (wc * 64 + (l & 15)) * 64 + cfr;
  int k0 = 0, kend = K;
  if (EP == 5) {
    int nz = gridDim.z;
    int ksp = ((K / 32 + nz - 1) / nz) * 32;
    k0 = blockIdx.z * ksp;
    kend = min(K, k0 + ksp);
  }
  int nsteps = (kend - k0) / 32;
  {  // prologue: stage tiles 0,1,2
#pragma unroll
    for (int tt = 0; tt < 3; ++tt) {
      size_t kb = (size_t)(k0 + tt * 32) * 2;
      char* sa = AsB + tt * 8192;
      char* sb = BsB + tt * 8192;
      load_lds16(Ag0 + kb, sa + tid * 16);
      load_lds16(Ag1 + kb, sa + 4096 + tid * 16);
      load_lds16(Bg0 + kb, sb + tid * 16);
      load_lds16(Bg1 + kb, sb + 4096 + tid * 16);
    }
  }
  int buf = 0;
  for (int t = 0; t < nsteps; ++t) {
    if (t + 2 < nsteps) {
      int nb = buf >= 1 ? buf - 1 : 2;  // (buf+2)%3
      size_t kb = (size_t)(k0 + (t + 2) * 32) * 2;
      load_lds16(Ag0 + kb, AsB + nb * 8192 + tid * 16);
      load_lds16(Ag1 + kb, AsB + nb * 8192 + 4096 + tid * 16);
      load_lds16(Bg0 + kb, BsB + nb * 8192 + tid * 16);
      load_lds16(Bg1 + kb, BsB + nb * 8192 + 4096 + tid * 16);
      asm volatile("s_waitcnt vmcnt(4)" ::: "memory");
    } else {
      asm volatile("s_waitcnt vmcnt(0)" ::: "memory");
    }
    __builtin_amdgcn_sched_barrier(0);
    __builtin_amdgcn_s_barrier();
    __builtin_amdgcn_sched_barrier(0);
    {
      const char* Ar = ArB + buf * 8192;
      const char* Br = BrB + buf * 8192;
      bf16x8 af[4], bfr[4];
#pragma unroll
      for (int m = 0; m < 4; ++m) af[m] = *(const bf16x8*)(Ar + m * 1024);
#pragma unroll
      for (int n = 0; n < 4; ++n) bfr[n] = *(const bf16x8*)(Br + n * 1024);
#pragma unroll
      for (int m = 0; m < 4; ++m)
#pragma unroll
        for (int n = 0; n < 4; ++n)
          acc[m][n] = __builtin_amdgcn_mfma_f32_16x16x32_bf16(af[m], bfr[n], acc[m][n], 0, 0, 0);
    }
    __builtin_amdgcn_sched_barrier(0);
    __builtin_amdgcn_s_barrier();
    __builtin_amdgcn_sched_barrier(0);
    buf = buf == 2 ? 0 : buf + 1;
  }
#pragma unroll
  for (int m = 0; m < 4; ++m) {
    int row = m0 + wr * 64 + m * 16 + (l >> 4) * 4;
#pragma unroll
    for (int n = 0; n < 4; ++n) {
      int col = n0 + wc * 64 + n * 16 + (l & 15);
      float bv = (EP == 5) ? 0.f : bias[col];
      if (EP == 4) {
        int region = (col >= 2304) ? 2 : (col >= 1152 ? 1 : 0);
        int cw = col - region * 1152;
        int hh = cw / 72;
        int dd = cw - hh * 72;
        u16* dst = (u16*)outp + (((size_t)region * NHEAD + hh) * SEQ) * HDIM + dd;
#pragma unroll
        for (int j = 0; j < 4; ++j)
          dst[(size_t)(row + j) * HDIM] = f2bf(acc[m][n][j] + bv);
      } else if (EP == 5) {
        u16* P = (u16*)outp + (size_t)blockIdx.z * M * N;
#pragma unroll
        for (int j = 0; j < 4; ++j)
          P[(size_t)(row + j) * N + col] = f2bf(acc[m][n][j]);
      } else {
#pragma unroll
        for (int j = 0; j < 4; ++j) {
          size_t idx = (size_t)(row + j) * N + col;
          float v = acc[m][n][j] + bv;
          if (EP == 1) ((u16*)outp)[idx] = f2bf(gelu_fast(v));
          else ((float*)outp)[idx] = v + resid[idx];
        }
      }
    }
  }
}

// ---------------- split-K reduce: out = sum(P[s]) + bias + resid (fp32) ----------------
template <int NS>
__global__ __launch_bounds__(256) void splitk_reduce_k(const u16* __restrict__ P,
                                                       const float* __restrict__ bias,
                                                       const float* __restrict__ resid,
                                                       float* __restrict__ out, int n4) {
  int i = blockIdx.x * 256 + threadIdx.x;
  if (i >= n4) return;
  size_t base = (size_t)i * 4;
  int col = (int)(base % HID);
  f32x4 a = {};
#pragma unroll
  for (int s = 0; s < NS; ++s) {
    u32x2 pv = *(const u32x2*)(P + (size_t)s * SEQ * HID + base);
    a[0] += bflo(pv[0]);
    a[1] += bfhi(pv[0]);
    a[2] += bflo(pv[1]);
    a[3] += bfhi(pv[1]);
  }
  f32x4 bv = *(const f32x4*)(bias + col);
  f32x4 rv = ((const f32x4*)resid)[i];
  ((f32x4*)out)[i] = a + bv + rv;
}

// ---------------- document-masked attention, MFMA + vectorized staging ----------------
__device__ __forceinline__ u32 swz(u32 a) { return a ^ (((a >> 8) & 7u) << 4); }

__global__ __launch_bounds__(256, 2) void attn_mfma_k(const u16* __restrict__ qkvh,
                                                      const int* __restrict__ se,
                                                      const float* __restrict__ zb,
                                                      u16* __restrict__ outb) {
  __shared__ u16 Ks[128 * 104];
  __shared__ u16 Vt[80 * 128];
  __shared__ u16 Ps[4][16 * 128];
  __shared__ int Sq[64], Eq[64];
  int tid = threadIdx.x, l = tid & 63, w = tid >> 6;
  int h = blockIdx.y, q0 = blockIdx.x * 64;
  const float scale = 0.1178511302f;
  const u16* Qh = qkvh + (size_t)h * SEQ * HDIM;
  const u16* Kh = qkvh + ((size_t)NHEAD + h) * SEQ * HDIM;
  const u16* Vh = qkvh + ((size_t)2 * NHEAD + h) * SEQ * HDIM;

  for (int i = tid; i < 512; i += 256) ((u32*)(Vt + 72 * 128))[i] = 0;

#pragma unroll
  for (int it = 0; it < 4; ++it) {
    int cw0 = it * 256 + w * 64;
    if (cw0 < 832) {
      int chunk = cw0 + l;
      int row = chunk / 13, c16 = chunk - row * 13;
      const void* src = (c16 < 9)
                            ? (const void*)(Qh + ((size_t)(q0 + row)) * HDIM + c16 * 8)
                            : (const void*)zb;
      load_lds16(src, (char*)Ks + (size_t)cw0 * 16);
    }
  }
  if (tid < 64) { Sq[tid] = se[2 * (q0 + tid)]; Eq[tid] = se[2 * (q0 + tid) + 1]; }
  __syncthreads();

  int sqj[4], eqj[4];
#pragma unroll
  for (int j = 0; j < 4; ++j) {
    int ql = w * 16 + (l >> 4) * 4 + j;
    sqj[j] = Sq[ql]; eqj[j] = Eq[ql];
  }
  const char* Aq = (const char*)Ks + (w * 16 + (l & 15)) * 208 + (l >> 4) * 16;
  bf16x8 aq[3];
#pragma unroll
  for (int dsl = 0; dsl < 3; ++dsl) aq[dsl] = *(const bf16x8*)(Aq + dsl * 64);
  __syncthreads();

  int kmin = se[2 * q0];
  int kmax = se[2 * (q0 + 63) + 1];
  f32x4 o[5] = {};
  float m_run[4], l_run[4];
#pragma unroll
  for (int j = 0; j < 4; ++j) { m_run[j] = -1e30f; l_run[j] = 0.f; }

  for (int kc = kmin; kc < kmax; kc += 128) {
#pragma unroll
    for (int it = 0; it < 7; ++it) {
      int cw0 = it * 256 + w * 64;
      if (cw0 < 1664) {
        int chunk = cw0 + l;
        int row = chunk / 13, c16 = chunk - row * 13;
        int krow = kc + row;
        const void* src = (c16 < 9 && krow < SEQ)
                              ? (const void*)(Kh + (size_t)krow * HDIM + c16 * 8)
                              : (const void*)zb;
        load_lds16(src, (char*)Ks + (size_t)cw0 * 16);
      }
    }
#pragma unroll
    for (int it = 0; it < 3; ++it) {
      int idx = it * 256 + tid;
      if (idx < 576) {
        int k2 = idx / 9, d8 = idx - k2 * 9;
        int kr0 = kc + 2 * k2, kr1 = kr0 + 1;
        kr0 = kr0 < SEQ ? kr0 : SEQ - 1;
        kr1 = kr1 < SEQ ? kr1 : SEQ - 1;
        u16x8 r0 = *(const u16x8*)(Vh + (size_t)kr0 * HDIM + d8 * 8);
        u16x8 r1 = *(const u16x8*)(Vh + (size_t)kr1 * HDIM + d8 * 8);
#pragma unroll
        for (int j = 0; j < 8; ++j) {
          u32 pr = (u32)r0[j] | ((u32)r1[j] << 16);
          *(u32*)((char*)Vt + swz((u32)(d8 * 8 + j) * 256 + (u32)k2 * 4)) = pr;
        }
      }
    }
    __syncthreads();

    f32x4 sf[8];
#pragma unroll
    for (int kt = 0; kt < 8; ++kt) {
      const char* Bk = (const char*)Ks + (kt * 16 + (l & 15)) * 208 + (l >> 4) * 16;
      f32x4 acc = {};
      acc = __builtin_amdgcn_mfma_f32_16x16x32_bf16(aq[0], *(const bf16x8*)Bk, acc, 0, 0, 0);
      acc = __builtin_amdgcn_mfma_f32_16x16x32_bf16(aq[1], *(const bf16x8*)(Bk + 64), acc, 0, 0, 0);
      acc = __builtin_amdgcn_mfma_f32_16x16x32_bf16(aq[2], *(const bf16x8*)(Bk + 128), acc, 0, 0, 0);
      sf[kt] = acc;
    }
    float mx[4] = {-1e30f, -1e30f, -1e30f, -1e30f};
#pragma unroll
    for (int kt = 0; kt < 8; ++kt) {
      int key = kc + kt * 16 + (l & 15);
#pragma unroll
      for (int j = 0; j < 4; ++j) {
        float s = sf[kt][j] * scale;
        bool valid = (key >= sqj[j]) && (key < eqj[j]);
        s = valid ? s : -1e30f;
        sf[kt][j] = s;
        mx[j] = fmaxf(mx[j], s);
      }
    }
#pragma unroll
    for (int j = 0; j < 4; ++j) {
      float m = mx[j];
      m = fmaxf(m, __shfl_xor(m, 1));
      m = fmaxf(m, __shfl_xor(m, 2));
      m = fmaxf(m, __shfl_xor(m, 4));
      m = fmaxf(m, __shfl_xor(m, 8));
      mx[j] = m;
    }
    float fz[4], ps[4];
#pragma unroll
    for (int j = 0; j < 4; ++j) {
      float mn = fmaxf(m_run[j], mx[j]);
      fz[j] = __expf(m_run[j] - mn);
      m_run[j] = mn;
      ps[j] = 0.f;
    }
#pragma unroll
    for (int kt = 0; kt < 8; ++kt)
#pragma unroll
      for (int j = 0; j < 4; ++j) {
        float s = sf[kt][j];
        float p = (s > -1e29f) ? __expf(s - m_run[j]) : 0.f;
        sf[kt][j] = p;
        ps[j] += p;
      }
#pragma unroll
    for (int j = 0; j < 4; ++j) {
      float p = ps[j];
      p += __shfl_xor(p, 1);
      p += __shfl_xor(p, 2);
      p += __shfl_xor(p, 4);
      p += __shfl_xor(p, 8);
      l_run[j] = l_run[j] * fz[j] + p;
#pragma unroll
      for (int dt = 0; dt < 5; ++dt) o[dt][j] *= fz[j];
    }
    char* PB = (char*)Ps[w];
#pragma unroll
    for (int kt = 0; kt < 8; ++kt)
#pragma unroll
      for (int j = 0; j < 4; ++j) {
        u32 a = (u32)((l >> 4) * 4 + j) * 256 + (u32)(kt * 16 + (l & 15)) * 2;
        *(u16*)(PB + swz(a)) = f2bf(sf[kt][j]);
      }
#pragma unroll
    for (int ks = 0; ks < 4; ++ks) {
      u32 aa = (u32)(l & 15) * 256 + (u32)((l >> 4) * 8 + ks * 32) * 2;
      bf16x8 ap = *(const bf16x8*)(PB + swz(aa));
#pragma unroll
      for (int dt = 0; dt < 5; ++dt) {
        u32 ba = (u32)(dt * 16 + (l & 15)) * 256 + (u32)((l >> 4) * 8 + ks * 32) * 2;
        bf16x8 bv = *(const bf16x8*)((const char*)Vt + swz(ba));
        o[dt] = __builtin_amdgcn_mfma_f32_16x16x32_bf16(ap, bv, o[dt], 0, 0, 0);
      }
    }
    __syncthreads();
  }

  float inv[4];
#pragma unroll
  for (int j = 0; j < 4; ++j) inv[j] = 1.f / l_run[j];
#pragma unroll
  for (int dt = 0; dt < 5; ++dt) {
    int d = dt * 16 + (l & 15);
    if (d < HDIM) {
#pragma unroll
      for (int j = 0; j < 4; ++j) {
        int q = q0 + w * 16 + (l >> 4) * 4 + j;
        outb[(size_t)q * HID + h * HDIM + d] = f2bf(o[dt][j] * inv[j]);
      }
    }
  }
}

// ---------------- workspace layout ----------------
constexpr size_t SZ_WQKV = (size_t)H3 * HID * 2;
constexpr size_t SZ_WO   = (size_t)HID * HID * 2;
constexpr size_t SZ_WF1  = (size_t)FFP * HID * 2;
constexpr size_t SZ_WF2  = (size_t)HID * FFP * 2;
constexpr size_t OFF_WQKV = 0;
constexpr size_t OFF_WO   = OFF_WQKV + SZ_WQKV;
constexpr size_t OFF_WF1  = OFF_WO + SZ_WO;
constexpr size_t OFF_BQKV = OFF_WF1 + SZ_WF1;
constexpr size_t OFF_BF1  = OFF_BQKV + (size_t)H3 * 4;
constexpr size_t OFF_SE   = OFF_BF1 + (size_t)FFP * 4;
constexpr size_t OFF_ZB   = OFF_SE + (size_t)SEQ * 2 * 4;
constexpr size_t OFF_XLN  = OFF_ZB + 64;
constexpr size_t OFF_QKV  = OFF_XLN + (size_t)SEQ * HID * 2;
constexpr size_t OFF_ACT  = OFF_QKV;  // ACT overlays QKV+AOUT (dead by FC1)
constexpr size_t OFF_AOUT = OFF_QKV + (size_t)SEQ * H3 * 2;
constexpr size_t OFF_HD   = OFF_AOUT + (size_t)SEQ * HID * 2;
constexpr size_t OFF_WF2  = OFF_HD + (size_t)SEQ * HID * 4;
constexpr size_t WS_NEED  = OFF_WF2 + SZ_WF2;
constexpr size_t OFF_P    = 0;  // split-K partials overlay dead prefix
static_assert(OFF_ACT + (size_t)SEQ * FFP * 2 <= OFF_HD, "ACT must not clobber HD");
static_assert(3 * (size_t)SEQ * HID * 2 <= OFF_QKV, "P must stay in dead prefix");

extern "C" void kernel_launch(void* const* d_in, const int* in_sizes, int n_in,
                              void* d_out, int out_size, void* d_ws, size_t ws_size,
                              hipStream_t stream) {
  const float* hs   = (const float*)d_in[0];
  const int*   ids  = (const int*)d_in[1];
  const float* q_w  = (const float*)d_in[2];
  const float* q_b  = (const float*)d_in[3];
  const float* k_w  = (const float*)d_in[4];
  const float* k_b  = (const float*)d_in[5];
  const float* v_w  = (const float*)d_in[6];
  const float* v_b  = (const float*)d_in[7];
  const float* o_w  = (const float*)d_in[8];
  const float* o_b  = (const float*)d_in[9];
  const float* ln1g = (const float*)d_in[10];
  const float* ln1b = (const float*)d_in[11];
  const float* ln2g = (const float*)d_in[12];
  const float* ln2b = (const float*)d_in[13];
  const float* f1w  = (const float*)d_in[14];
  const float* f1b  = (const float*)d_in[15];
  const float* f2w  = (const float*)d_in[16];
  const float* f2b  = (const float*)d_in[17];

  if (ws_size < WS_NEED) return;

  char* ws = (char*)d_ws;
  u16*   Wqkv = (u16*)(ws + OFF_WQKV);
  u16*   Wo   = (u16*)(ws + OFF_WO);
  u16*   Wf1  = (u16*)(ws + OFF_WF1);
  u16*   Wf2  = (u16*)(ws + OFF_WF2);
  float* Bqkv = (float*)(ws + OFF_BQKV);
  float* Bf1  = (float*)(ws + OFF_BF1);
  int*   SE   = (int*)(ws + OFF_SE);
  float* ZB   = (float*)(ws + OFF_ZB);
  u16*   XLN  = (u16*)(ws + OFF_XLN);
  u16*   QKVh = (u16*)(ws + OFF_QKV);
  u16*   ACT  = (u16*)(ws + OFF_ACT);
  u16*   AOUT = (u16*)(ws + OFF_AOUT);
  float* HD   = (float*)(ws + OFF_HD);
  u16*   Pp   = (u16*)(ws + OFF_P);

  prep_k<<<dim3((FFP + 255) / 256), dim3(256), 0, stream>>>(ids, q_b, k_b, v_b, f1b, SE, Bqkv,
                                                            Bf1, ZB);
  // merged weight converts: seg 0-3 qkvo (1296 blocks used), seg 4-5 fc1/fc2 (4896)
  cvt_all_k<<<dim3((FFP * HID / 4 + 255) / 256, 6), dim3(256), 0, stream>>>(
      q_w, k_w, v_w, o_w, f1w, f2w, Wqkv, Wf1, Wf2);

  // LN1
  ln_k<<<dim3(SEQ), dim3(256), 0, stream>>>(hs, ln1g, ln1b, XLN);
  // QKV projection -> head-major scatter (grid 27x32)
  gemm_bt<4><<<dim3(H3 / 128, SEQ / 128), dim3(256), 0, stream>>>(XLN, Wqkv, QKVh, Bqkv, nullptr,
                                                                  SEQ, H3, HID);
  // doc-masked attention (MFMA)
  attn_mfma_k<<<dim3(SEQ / 64, NHEAD), dim3(256), 0, stream>>>(QKVh, SE, ZB, AOUT);
  // O projection + residual -> fp32 hidden (grid 9x32)
  gemm_bt<2><<<dim3(HID / 128, SEQ / 128), dim3(256), 0, stream>>>(AOUT, Wo, HD, o_b, hs,
                                                                   SEQ, HID, HID);
  // LN2
  ln_k<<<dim3(SEQ), dim3(256), 0, stream>>>(HD, ln2g, ln2b, XLN);
  // FC1 + GELU (grid 34x32)
  gemm_bt<1><<<dim3(FFP / 128, SEQ / 128), dim3(256), 0, stream>>>(XLN, Wf1, ACT, Bf1, nullptr,
                                                                   SEQ, FFP, HID);
  // FC2 split-K=3 partials (grid 9x32x3)
  gemm_bt<5><<<dim3(HID / 128, SEQ / 128, 3), dim3(256), 0, stream>>>(ACT, Wf2, Pp, nullptr,
                                                                      nullptr, SEQ, HID, FFP);
  // reduce + bias + residual -> fp32 output
  splitk_reduce_k<3><<<dim3(SEQ * HID / 4 / 256), dim3(256), 0, stream>>>(Pp, f2b, HD,
                                                                          (float*)d_out,
                                                                          SEQ * HID / 4);
}

// Round 15
// 283.910 us; speedup vs baseline: 1.0198x; 1.0057x over previous
//
#include <hip/hip_runtime.h>

typedef unsigned short u16;
typedef unsigned int u32;
typedef __attribute__((ext_vector_type(8))) __bf16 bf16x8;
typedef __attribute__((ext_vector_type(8))) u16 u16x8;
typedef __attribute__((ext_vector_type(4))) float f32x4;
typedef __attribute__((ext_vector_type(2))) u32 u32x2;

#define SEQ 4096
#define HID 1152
#define NHEAD 16
#define HDIM 72
#define FF 4304
#define FFP 4352
#define H3 3456

__device__ __forceinline__ u16 f2bf(float f) {
  u32 u = __builtin_bit_cast(u32, f);
  u32 r = u + 0x7fffu + ((u >> 16) & 1u);
  return (u16)(r >> 16);
}
__device__ __forceinline__ float bf2f(u16 h) {
  return __builtin_bit_cast(float, (u32)h << 16);
}
__device__ __forceinline__ float bflo(u32 u) { return __builtin_bit_cast(float, u << 16); }
__device__ __forceinline__ float bfhi(u32 u) { return __builtin_bit_cast(float, u & 0xffff0000u); }

typedef const __attribute__((address_space(1))) void* gas_t;
typedef __attribute__((address_space(3))) void* las_t;
__device__ __forceinline__ void load_lds16(const void* g, void* l) {
  __builtin_amdgcn_global_load_lds((gas_t)(unsigned long long)g,
                                   (las_t)(u32)(unsigned long long)l, 16, 0, 0);
}

__device__ __forceinline__ float gelu_fast(float x) {
  float z = 0.7978845608f * (x + 0.044715f * x * x * x);
  return x / (1.f + __expf(-2.f * z));
}

// ---------------- merged weight converts (one launch, 6 segments) ----------------
__global__ __launch_bounds__(256) void cvt_all_k(const float* __restrict__ qw,
                                                 const float* __restrict__ kw,
                                                 const float* __restrict__ vw,
                                                 const float* __restrict__ ow,
                                                 const float* __restrict__ f1w,
                                                 const float* __restrict__ f2w,
                                                 u16* __restrict__ wqkv,
                                                 u16* __restrict__ wf1,
                                                 u16* __restrict__ wf2) {
  int seg = blockIdx.y;
  int i = blockIdx.x * 256 + threadIdx.x;
  u32x2 o;
  if (seg < 4) {
    int n4 = HID * HID / 4;
    if (i >= n4) return;
    const float* in = (seg == 0) ? qw : (seg == 1) ? kw : (seg == 2) ? vw : ow;
    f32x4 f = ((const f32x4*)in)[i];
    o[0] = (u32)f2bf(f[0]) | ((u32)f2bf(f[1]) << 16);
    o[1] = (u32)f2bf(f[2]) | ((u32)f2bf(f[3]) << 16);
    ((u32x2*)(wqkv + (size_t)seg * HID * HID))[i] = o;
  } else if (seg == 4) {
    int n4 = FFP * HID / 4;
    if (i >= n4) return;
    int c = i * 4;
    if (c < FF * HID) {
      f32x4 f = *(const f32x4*)(f1w + c);
      o[0] = (u32)f2bf(f[0]) | ((u32)f2bf(f[1]) << 16);
      o[1] = (u32)f2bf(f[2]) | ((u32)f2bf(f[3]) << 16);
    } else {
      o[0] = 0; o[1] = 0;
    }
    ((u32x2*)wf1)[i] = o;
  } else {
    int n4 = HID * FFP / 4;
    if (i >= n4) return;
    int idx = i * 4;
    int r = idx / FFP;
    int c = idx - r * FFP;
    if (c < FF) {
      f32x4 f = *(const f32x4*)(f2w + (size_t)r * FF + c);
      o[0] = (u32)f2bf(f[0]) | ((u32)f2bf(f[1]) << 16);
      o[1] = (u32)f2bf(f[2]) | ((u32)f2bf(f[3]) << 16);
    } else {
      o[0] = 0; o[1] = 0;
    }
    ((u32x2*)wf2)[i] = o;
  }
}

// ---------------- prep: doc ranges + packed biases + zero buf ----------------
__global__ __launch_bounds__(256) void prep_k(const int* __restrict__ ids,
                                              const float* __restrict__ qb,
                                              const float* __restrict__ kb,
                                              const float* __restrict__ vb,
                                              const float* __restrict__ f1b,
                                              int* __restrict__ se,
                                              float* __restrict__ bqkv,
                                              float* __restrict__ bf1,
                                              float* __restrict__ zbuf) {
  int i = blockIdx.x * 256 + threadIdx.x;
  if (i < H3) bqkv[i] = (i < HID) ? qb[i] : (i < 2 * HID ? kb[i - HID] : vb[i - 2 * HID]);
  if (i < FFP) bf1[i] = (i < FF) ? f1b[i] : 0.f;
  if (i < 16) zbuf[i] = 0.f;
  if (i < SEQ) {
    int id = ids[i];
    int lo = 0, hi = SEQ;
    while (lo < hi) { int mid = (lo + hi) >> 1; if (ids[mid] < id) lo = mid + 1; else hi = mid; }
    int s = lo;
    lo = 0; hi = SEQ;
    while (lo < hi) { int mid = (lo + hi) >> 1; if (ids[mid] <= id) lo = mid + 1; else hi = mid; }
    se[2 * i] = s;
    se[2 * i + 1] = lo;
  }
}

// ---------------- LayerNorm fp32 -> bf16 ----------------
__global__ __launch_bounds__(256) void ln_k(const float* __restrict__ x,
                                            const float* __restrict__ g,
                                            const float* __restrict__ b,
                                            u16* __restrict__ y) {
  __shared__ float sred[8];
  int row = blockIdx.x, tid = threadIdx.x;
  const f32x4* xr = (const f32x4*)(x + (size_t)row * HID);
  f32x4 v0 = {}, v1 = {};
  float s = 0.f, s2 = 0.f;
  int c0 = tid, c1 = tid + 256;
  v0 = xr[c0];
  if (c1 < 288) v1 = xr[c1];
#pragma unroll
  for (int j = 0; j < 4; ++j) { s += v0[j] + v1[j]; s2 += v0[j] * v0[j] + v1[j] * v1[j]; }
#pragma unroll
  for (int sh = 32; sh; sh >>= 1) { s += __shfl_xor(s, sh); s2 += __shfl_xor(s2, sh); }
  if ((tid & 63) == 0) { sred[tid >> 6] = s; sred[4 + (tid >> 6)] = s2; }
  __syncthreads();
  s = sred[0] + sred[1] + sred[2] + sred[3];
  s2 = sred[4] + sred[5] + sred[6] + sred[7];
  float mu = s * (1.f / HID);
  float rs = rsqrtf(s2 * (1.f / HID) - mu * mu + 1e-6f);
  u16* yr = y + (size_t)row * HID;
  const f32x4* g4 = (const f32x4*)g;
  const f32x4* b4 = (const f32x4*)b;
  {
    f32x4 gv = g4[c0], bv = b4[c0];
    u32x2 o;
    o[0] = (u32)f2bf((v0[0] - mu) * rs * gv[0] + bv[0]) |
           ((u32)f2bf((v0[1] - mu) * rs * gv[1] + bv[1]) << 16);
    o[1] = (u32)f2bf((v0[2] - mu) * rs * gv[2] + bv[2]) |
           ((u32)f2bf((v0[3] - mu) * rs * gv[3] + bv[3]) << 16);
    *(u32x2*)(yr + c0 * 4) = o;
  }
  if (c1 < 288) {
    f32x4 gv = g4[c1], bv = b4[c1];
    u32x2 o;
    o[0] = (u32)f2bf((v1[0] - mu) * rs * gv[0] + bv[0]) |
           ((u32)f2bf((v1[1] - mu) * rs * gv[1] + bv[1]) << 16);
    o[1] = (u32)f2bf((v1[2] - mu) * rs * gv[2] + bv[2]) |
           ((u32)f2bf((v1[3] - mu) * rs * gv[3] + bv[3]) << 16);
    *(u32x2*)(yr + c1 * 4) = o;
  }
}

// ---------------- GEMM: ring-3 BK=32 with PACKED conflict-free LDS ----------------
// LDS tile per op: [64 phys rows][128B]. Phys (r,c16) holds logical chunk
// lc = c16 ^ (r&7); lc = half*4 + kchunk -> logical row r + half*64, k-bytes kchunk*16.
// Staging: dest linear in lane (gload_lds constraint); per-lane SOURCE from inverse map.
// Fragment read: r = m*16+(l&15), c16 = (half*4 + (l>>4)) ^ (l&7); bank = f(c16) only
// -> 8 chunks x 2 lanes = 2-way = free. Same involution both sides (G21).
// Ring/sync/epilogues identical to the 285.5us best.
// EP: 1 = bf16(gelu(acc+bias)); 2 = f32(acc+bias+resid);
// EP: 4 = bf16(acc+bias) head-major QKV scatter; EP: 5 = split-K partial bf16
template <int EP>
__global__ __launch_bounds__(256, 3) void gemm_bt(const u16* __restrict__ A,
                                                  const u16* __restrict__ B,
                                                  void* __restrict__ outp,
                                                  const float* __restrict__ bias,
                                                  const float* __restrict__ resid,
                                                  int M, int N, int K) {
  __shared__ u16 As[3 * 64 * 64];  // 3 slots x 8KB
  __shared__ u16 Bs[3 * 64 * 64];
  int tid = threadIdx.x;
  int l = tid & 63, w = tid >> 6;
  int nxy = gridDim.x * gridDim.y;
  int bidf = blockIdx.y * gridDim.x + blockIdx.x;
  int cpx = nxy >> 3;
  bidf = (bidf & 7) * cpx + (bidf >> 3);
  int m0 = (bidf / gridDim.x) * 128;
  int n0 = (bidf % gridDim.x) * 128;
  int wr = w >> 1, wc = w & 1;
  f32x4 acc[4][4] = {};
  // staging source map for chunk indices ci0=tid, ci1=256+tid
  int ci0 = tid, ci1 = 256 + tid;
  int r0 = ci0 >> 3, c0c = ci0 & 7, lc0 = c0c ^ (r0 & 7);
  int lrow0 = r0 + (lc0 >> 2) * 64, ko0 = (lc0 & 3) * 16;
  int r1 = ci1 >> 3, c1c = ci1 & 7, lc1 = c1c ^ (r1 & 7);
  int lrow1 = r1 + (lc1 >> 2) * 64, ko1 = (lc1 & 3) * 16;
  const char* Ag0 = (const char*)A + (size_t)(m0 + lrow0) * K * 2 + ko0;
  const char* Ag1 = (const char*)A + (size_t)(m0 + lrow1) * K * 2 + ko1;
  const char* Bg0 = (const char*)B + (size_t)(n0 + lrow0) * K * 2 + ko0;
  const char* Bg1 = (const char*)B + (size_t)(n0 + lrow1) * K * 2 + ko1;
  char* AsB = (char*)As;
  char* BsB = (char*)Bs;
  // fragment read: row r=m*16+(l&15) (phys), chunk (half*4 + kc) ^ (l&7)
  int cA = ((wr * 4) + (l >> 4)) ^ (l & 7);
  int cB = ((wc * 4) + (l >> 4)) ^ (l & 7);
  const char* ArB = (const char*)As + (size_t)(l & 15) * 128 + cA * 16;
  const char* BrB = (const char*)Bs + (size_t)(l & 15) * 128 + cB * 16;
  int k0 = 0, kend = K;
  if (EP == 5) {
    int nz = gridDim.z;
    int ksp = ((K / 32 + nz - 1) / nz) * 32;
    k0 = blockIdx.z * ksp;
    kend = min(K, k0 + ksp);
  }
  int nsteps = (kend - k0) / 32;
  {  // prologue: stage tiles 0,1,2
#pragma unroll
    for (int tt = 0; tt < 3; ++tt) {
      size_t kb = (size_t)(k0 + tt * 32) * 2;
      char* sa = AsB + tt * 8192;
      char* sb = BsB + tt * 8192;
      load_lds16(Ag0 + kb, sa + tid * 16);
      load_lds16(Ag1 + kb, sa + 4096 + tid * 16);
      load_lds16(Bg0 + kb, sb + tid * 16);
      load_lds16(Bg1 + kb, sb + 4096 + tid * 16);
    }
  }
  int buf = 0;
  for (int t = 0; t < nsteps; ++t) {
    if (t + 2 < nsteps) {
      int nb = buf >= 1 ? buf - 1 : 2;  // (buf+2)%3
      size_t kb = (size_t)(k0 + (t + 2) * 32) * 2;
      load_lds16(Ag0 + kb, AsB + nb * 8192 + tid * 16);
      load_lds16(Ag1 + kb, AsB + nb * 8192 + 4096 + tid * 16);
      load_lds16(Bg0 + kb, BsB + nb * 8192 + tid * 16);
      load_lds16(Bg1 + kb, BsB + nb * 8192 + 4096 + tid * 16);
      asm volatile("s_waitcnt vmcnt(4)" ::: "memory");
    } else {
      asm volatile("s_waitcnt vmcnt(0)" ::: "memory");
    }
    __builtin_amdgcn_sched_barrier(0);
    __builtin_amdgcn_s_barrier();
    __builtin_amdgcn_sched_barrier(0);
    {
      const char* Ar = ArB + buf * 8192;
      const char* Br = BrB + buf * 8192;
      bf16x8 af[4], bfr[4];
#pragma unroll
      for (int m = 0; m < 4; ++m) af[m] = *(const bf16x8*)(Ar + m * 2048);
#pragma unroll
      for (int n = 0; n < 4; ++n) bfr[n] = *(const bf16x8*)(Br + n * 2048);
#pragma unroll
      for (int m = 0; m < 4; ++m)
#pragma unroll
        for (int n = 0; n < 4; ++n)
          acc[m][n] = __builtin_amdgcn_mfma_f32_16x16x32_bf16(af[m], bfr[n], acc[m][n], 0, 0, 0);
    }
    __builtin_amdgcn_sched_barrier(0);
    __builtin_amdgcn_s_barrier();
    __builtin_amdgcn_sched_barrier(0);
    buf = buf == 2 ? 0 : buf + 1;
  }
#pragma unroll
  for (int m = 0; m < 4; ++m) {
    int row = m0 + wr * 64 + m * 16 + (l >> 4) * 4;
#pragma unroll
    for (int n = 0; n < 4; ++n) {
      int col = n0 + wc * 64 + n * 16 + (l & 15);
      float bv = (EP == 5) ? 0.f : bias[col];
      if (EP == 4) {
        int region = (col >= 2304) ? 2 : (col >= 1152 ? 1 : 0);
        int cw = col - region * 1152;
        int hh = cw / 72;
        int dd = cw - hh * 72;
        u16* dst = (u16*)outp + (((size_t)region * NHEAD + hh) * SEQ) * HDIM + dd;
#pragma unroll
        for (int j = 0; j < 4; ++j)
          dst[(size_t)(row + j) * HDIM] = f2bf(acc[m][n][j] + bv);
      } else if (EP == 5) {
        u16* P = (u16*)outp + (size_t)blockIdx.z * M * N;
#pragma unroll
        for (int j = 0; j < 4; ++j)
          P[(size_t)(row + j) * N + col] = f2bf(acc[m][n][j]);
      } else {
#pragma unroll
        for (int j = 0; j < 4; ++j) {
          size_t idx = (size_t)(row + j) * N + col;
          float v = acc[m][n][j] + bv;
          if (EP == 1) ((u16*)outp)[idx] = f2bf(gelu_fast(v));
          else ((float*)outp)[idx] = v + resid[idx];
        }
      }
    }
  }
}

// ---------------- split-K reduce: out = sum(P[s]) + bias + resid (fp32) ----------------
template <int NS>
__global__ __launch_bounds__(256) void splitk_reduce_k(const u16* __restrict__ P,
                                                       const float* __restrict__ bias,
                                                       const float* __restrict__ resid,
                                                       float* __restrict__ out, int n4) {
  int i = blockIdx.x * 256 + threadIdx.x;
  if (i >= n4) return;
  size_t base = (size_t)i * 4;
  int col = (int)(base % HID);
  f32x4 a = {};
#pragma unroll
  for (int s = 0; s < NS; ++s) {
    u32x2 pv = *(const u32x2*)(P + (size_t)s * SEQ * HID + base);
    a[0] += bflo(pv[0]);
    a[1] += bfhi(pv[0]);
    a[2] += bflo(pv[1]);
    a[3] += bfhi(pv[1]);
  }
  f32x4 bv = *(const f32x4*)(bias + col);
  f32x4 rv = ((const f32x4*)resid)[i];
  ((f32x4*)out)[i] = a + bv + rv;
}

// ---------------- document-masked attention, MFMA + vectorized staging ----------------
__device__ __forceinline__ u32 swz(u32 a) { return a ^ (((a >> 8) & 7u) << 4); }

__global__ __launch_bounds__(256, 2) void attn_mfma_k(const u16* __restrict__ qkvh,
                                                      const int* __restrict__ se,
                                                      const float* __restrict__ zb,
                                                      u16* __restrict__ outb) {
  __shared__ u16 Ks[128 * 104];
  __shared__ u16 Vt[80 * 128];
  __shared__ u16 Ps[4][16 * 128];
  __shared__ int Sq[64], Eq[64];
  int tid = threadIdx.x, l = tid & 63, w = tid >> 6;
  int h = blockIdx.y, q0 = blockIdx.x * 64;
  const float scale = 0.1178511302f;
  const u16* Qh = qkvh + (size_t)h * SEQ * HDIM;
  const u16* Kh = qkvh + ((size_t)NHEAD + h) * SEQ * HDIM;
  const u16* Vh = qkvh + ((size_t)2 * NHEAD + h) * SEQ * HDIM;

  for (int i = tid; i < 512; i += 256) ((u32*)(Vt + 72 * 128))[i] = 0;

#pragma unroll
  for (int it = 0; it < 4; ++it) {
    int cw0 = it * 256 + w * 64;
    if (cw0 < 832) {
      int chunk = cw0 + l;
      int row = chunk / 13, c16 = chunk - row * 13;
      const void* src = (c16 < 9)
                            ? (const void*)(Qh + ((size_t)(q0 + row)) * HDIM + c16 * 8)
                            : (const void*)zb;
      load_lds16(src, (char*)Ks + (size_t)cw0 * 16);
    }
  }
  if (tid < 64) { Sq[tid] = se[2 * (q0 + tid)]; Eq[tid] = se[2 * (q0 + tid) + 1]; }
  __syncthreads();

  int sqj[4], eqj[4];
#pragma unroll
  for (int j = 0; j < 4; ++j) {
    int ql = w * 16 + (l >> 4) * 4 + j;
    sqj[j] = Sq[ql]; eqj[j] = Eq[ql];
  }
  const char* Aq = (const char*)Ks + (w * 16 + (l & 15)) * 208 + (l >> 4) * 16;
  bf16x8 aq[3];
#pragma unroll
  for (int dsl = 0; dsl < 3; ++dsl) aq[dsl] = *(const bf16x8*)(Aq + dsl * 64);
  __syncthreads();

  int kmin = se[2 * q0];
  int kmax = se[2 * (q0 + 63) + 1];
  f32x4 o[5] = {};
  float m_run[4], l_run[4];
#pragma unroll
  for (int j = 0; j < 4; ++j) { m_run[j] = -1e30f; l_run[j] = 0.f; }

  for (int kc = kmin; kc < kmax; kc += 128) {
#pragma unroll
    for (int it = 0; it < 7; ++it) {
      int cw0 = it * 256 + w * 64;
      if (cw0 < 1664) {
        int chunk = cw0 + l;
        int row = chunk / 13, c16 = chunk - row * 13;
        int krow = kc + row;
        const void* src = (c16 < 9 && krow < SEQ)
                              ? (const void*)(Kh + (size_t)krow * HDIM + c16 * 8)
                              : (const void*)zb;
        load_lds16(src, (char*)Ks + (size_t)cw0 * 16);
      }
    }
#pragma unroll
    for (int it = 0; it < 3; ++it) {
      int idx = it * 256 + tid;
      if (idx < 576) {
        int k2 = idx / 9, d8 = idx - k2 * 9;
        int kr0 = kc + 2 * k2, kr1 = kr0 + 1;
        kr0 = kr0 < SEQ ? kr0 : SEQ - 1;
        kr1 = kr1 < SEQ ? kr1 : SEQ - 1;
        u16x8 r0 = *(const u16x8*)(Vh + (size_t)kr0 * HDIM + d8 * 8);
        u16x8 r1 = *(const u16x8*)(Vh + (size_t)kr1 * HDIM + d8 * 8);
#pragma unroll
        for (int j = 0; j < 8; ++j) {
          u32 pr = (u32)r0[j] | ((u32)r1[j] << 16);
          *(u32*)((char*)Vt + swz((u32)(d8 * 8 + j) * 256 + (u32)k2 * 4)) = pr;
        }
      }
    }
    __syncthreads();

    f32x4 sf[8];
#pragma unroll
    for (int kt = 0; kt < 8; ++kt) {
      const char* Bk = (const char*)Ks + (kt * 16 + (l & 15)) * 208 + (l >> 4) * 16;
      f32x4 acc = {};
      acc = __builtin_amdgcn_mfma_f32_16x16x32_bf16(aq[0], *(const bf16x8*)Bk, acc, 0, 0, 0);
      acc = __builtin_amdgcn_mfma_f32_16x16x32_bf16(aq[1], *(const bf16x8*)(Bk + 64), acc, 0, 0, 0);
      acc = __builtin_amdgcn_mfma_f32_16x16x32_bf16(aq[2], *(const bf16x8*)(Bk + 128), acc, 0, 0, 0);
      sf[kt] = acc;
    }
    float mx[4] = {-1e30f, -1e30f, -1e30f, -1e30f};
#pragma unroll
    for (int kt = 0; kt < 8; ++kt) {
      int key = kc + kt * 16 + (l & 15);
#pragma unroll
      for (int j = 0; j < 4; ++j) {
        float s = sf[kt][j] * scale;
        bool valid = (key >= sqj[j]) && (key < eqj[j]);
        s = valid ? s : -1e30f;
        sf[kt][j] = s;
        mx[j] = fmaxf(mx[j], s);
      }
    }
#pragma unroll
    for (int j = 0; j < 4; ++j) {
      float m = mx[j];
      m = fmaxf(m, __shfl_xor(m, 1));
      m = fmaxf(m, __shfl_xor(m, 2));
      m = fmaxf(m, __shfl_xor(m, 4));
      m = fmaxf(m, __shfl_xor(m, 8));
      mx[j] = m;
    }
    float fz[4], ps[4];
#pragma unroll
    for (int j = 0; j < 4; ++j) {
      float mn = fmaxf(m_run[j], mx[j]);
      fz[j] = __expf(m_run[j] - mn);
      m_run[j] = mn;
      ps[j] = 0.f;
    }
#pragma unroll
    for (int kt = 0; kt < 8; ++kt)
#pragma unroll
      for (int j = 0; j < 4; ++j) {
        float s = sf[kt][j];
        float p = (s > -1e29f) ? __expf(s - m_run[j]) : 0.f;
        sf[kt][j] = p;
        ps[j] += p;
      }
#pragma unroll
    for (int j = 0; j < 4; ++j) {
      float p = ps[j];
      p += __shfl_xor(p, 1);
      p += __shfl_xor(p, 2);
      p += __shfl_xor(p, 4);
      p += __shfl_xor(p, 8);
      l_run[j] = l_run[j] * fz[j] + p;
#pragma unroll
      for (int dt = 0; dt < 5; ++dt) o[dt][j] *= fz[j];
    }
    char* PB = (char*)Ps[w];
#pragma unroll
    for (int kt = 0; kt < 8; ++kt)
#pragma unroll
      for (int j = 0; j < 4; ++j) {
        u32 a = (u32)((l >> 4) * 4 + j) * 256 + (u32)(kt * 16 + (l & 15)) * 2;
        *(u16*)(PB + swz(a)) = f2bf(sf[kt][j]);
      }
#pragma unroll
    for (int ks = 0; ks < 4; ++ks) {
      u32 aa = (u32)(l & 15) * 256 + (u32)((l >> 4) * 8 + ks * 32) * 2;
      bf16x8 ap = *(const bf16x8*)(PB + swz(aa));
#pragma unroll
      for (int dt = 0; dt < 5; ++dt) {
        u32 ba = (u32)(dt * 16 + (l & 15)) * 256 + (u32)((l >> 4) * 8 + ks * 32) * 2;
        bf16x8 bv = *(const bf16x8*)((const char*)Vt + swz(ba));
        o[dt] = __builtin_amdgcn_mfma_f32_16x16x32_bf16(ap, bv, o[dt], 0, 0, 0);
      }
    }
    __syncthreads();
  }

  float inv[4];
#pragma unroll
  for (int j = 0; j < 4; ++j) inv[j] = 1.f / l_run[j];
#pragma unroll
  for (int dt = 0; dt < 5; ++dt) {
    int d = dt * 16 + (l & 15);
    if (d < HDIM) {
#pragma unroll
      for (int j = 0; j < 4; ++j) {
        int q = q0 + w * 16 + (l >> 4) * 4 + j;
        outb[(size_t)q * HID + h * HDIM + d] = f2bf(o[dt][j] * inv[j]);
      }
    }
  }
}

// ---------------- workspace layout ----------------
constexpr size_t SZ_WQKV = (size_t)H3 * HID * 2;
constexpr size_t SZ_WO   = (size_t)HID * HID * 2;
constexpr size_t SZ_WF1  = (size_t)FFP * HID * 2;
constexpr size_t SZ_WF2  = (size_t)HID * FFP * 2;
constexpr size_t OFF_WQKV = 0;
constexpr size_t OFF_WO   = OFF_WQKV + SZ_WQKV;
constexpr size_t OFF_WF1  = OFF_WO + SZ_WO;
constexpr size_t OFF_BQKV = OFF_WF1 + SZ_WF1;
constexpr size_t OFF_BF1  = OFF_BQKV + (size_t)H3 * 4;
constexpr size_t OFF_SE   = OFF_BF1 + (size_t)FFP * 4;
constexpr size_t OFF_ZB   = OFF_SE + (size_t)SEQ * 2 * 4;
constexpr size_t OFF_XLN  = OFF_ZB + 64;
constexpr size_t OFF_QKV  = OFF_XLN + (size_t)SEQ * HID * 2;
constexpr size_t OFF_ACT  = OFF_QKV;  // ACT overlays QKV+AOUT (dead by FC1)
constexpr size_t OFF_AOUT = OFF_QKV + (size_t)SEQ * H3 * 2;
constexpr size_t OFF_HD   = OFF_AOUT + (size_t)SEQ * HID * 2;
constexpr size_t OFF_WF2  = OFF_HD + (size_t)SEQ * HID * 4;
constexpr size_t WS_NEED  = OFF_WF2 + SZ_WF2;
constexpr size_t OFF_P    = 0;  // split-K partials overlay dead prefix
static_assert(OFF_ACT + (size_t)SEQ * FFP * 2 <= OFF_HD, "ACT must not clobber HD");
static_assert(3 * (size_t)SEQ * HID * 2 <= OFF_QKV, "P must stay in dead prefix");

extern "C" void kernel_launch(void* const* d_in, const int* in_sizes, int n_in,
                              void* d_out, int out_size, void* d_ws, size_t ws_size,
                              hipStream_t stream) {
  const float* hs   = (const float*)d_in[0];
  const int*   ids  = (const int*)d_in[1];
  const float* q_w  = (const float*)d_in[2];
  const float* q_b  = (const float*)d_in[3];
  const float* k_w  = (const float*)d_in[4];
  const float* k_b  = (const float*)d_in[5];
  const float* v_w  = (const float*)d_in[6];
  const float* v_b  = (const float*)d_in[7];
  const float* o_w  = (const float*)d_in[8];
  const float* o_b  = (const float*)d_in[9];
  const float* ln1g = (const float*)d_in[10];
  const float* ln1b = (const float*)d_in[11];
  const float* ln2g = (const float*)d_in[12];
  const float* ln2b = (const float*)d_in[13];
  const float* f1w  = (const float*)d_in[14];
  const float* f1b  = (const float*)d_in[15];
  const float* f2w  = (const float*)d_in[16];
  const float* f2b  = (const float*)d_in[17];

  if (ws_size < WS_NEED) return;

  char* ws = (char*)d_ws;
  u16*   Wqkv = (u16*)(ws + OFF_WQKV);
  u16*   Wo   = (u16*)(ws + OFF_WO);
  u16*   Wf1  = (u16*)(ws + OFF_WF1);
  u16*   Wf2  = (u16*)(ws + OFF_WF2);
  float* Bqkv = (float*)(ws + OFF_BQKV);
  float* Bf1  = (float*)(ws + OFF_BF1);
  int*   SE   = (int*)(ws + OFF_SE);
  float* ZB   = (float*)(ws + OFF_ZB);
  u16*   XLN  = (u16*)(ws + OFF_XLN);
  u16*   QKVh = (u16*)(ws + OFF_QKV);
  u16*   ACT  = (u16*)(ws + OFF_ACT);
  u16*   AOUT = (u16*)(ws + OFF_AOUT);
  float* HD   = (float*)(ws + OFF_HD);
  u16*   Pp   = (u16*)(ws + OFF_P);

  prep_k<<<dim3((FFP + 255) / 256), dim3(256), 0, stream>>>(ids, q_b, k_b, v_b, f1b, SE, Bqkv,
                                                            Bf1, ZB);
  cvt_all_k<<<dim3((FFP * HID / 4 + 255) / 256, 6), dim3(256), 0, stream>>>(
      q_w, k_w, v_w, o_w, f1w, f2w, Wqkv, Wf1, Wf2);

  // LN1
  ln_k<<<dim3(SEQ), dim3(256), 0, stream>>>(hs, ln1g, ln1b, XLN);
  // QKV projection -> head-major scatter (grid 27x32)
  gemm_bt<4><<<dim3(H3 / 128, SEQ / 128), dim3(256), 0, stream>>>(XLN, Wqkv, QKVh, Bqkv, nullptr,
                                                                  SEQ, H3, HID);
  // doc-masked attention (MFMA)
  attn_mfma_k<<<dim3(SEQ / 64, NHEAD), dim3(256), 0, stream>>>(QKVh, SE, ZB, AOUT);
  // O projection + residual -> fp32 hidden (grid 9x32)
  gemm_bt<2><<<dim3(HID / 128, SEQ / 128), dim3(256), 0, stream>>>(AOUT, Wo, HD, o_b, hs,
                                                                   SEQ, HID, HID);
  // LN2
  ln_k<<<dim3(SEQ), dim3(256), 0, stream>>>(HD, ln2g, ln2b, XLN);
  // FC1 + GELU (grid 34x32)
  gemm_bt<1><<<dim3(FFP / 128, SEQ / 128), dim3(256), 0, stream>>>(XLN, Wf1, ACT, Bf1, nullptr,
                                                                   SEQ, FFP, HID);
  // FC2 split-K=3 partials (grid 9x32x3)
  gemm_bt<5><<<dim3(HID / 128, SEQ / 128, 3), dim3(256), 0, stream>>>(ACT, Wf2, Pp, nullptr,
                                                                      nullptr, SEQ, HID, FFP);
  // reduce + bias + residual -> fp32 output
  splitk_reduce_k<3><<<dim3(SEQ * HID / 4 / 256), dim3(256), 0, stream>>>(Pp, f2b, HD,
                                                                          (float*)d_out,
                                                                          SEQ * HID / 4);
}